// Round 5
// baseline (565.864 us; speedup 1.0000x reference)
//
#include <hip/hip_runtime.h>
#include <math.h>

#define EMBED 1536
#define BN 64
#define XS_STRIDE 1544   // shorts; row stride 3088 B -> 16B aligned (ds_read_b128 ok)
#define GS_STRIDE 80     // shorts; row stride 160 B -> 16B aligned
#define NBLOCKS 256      // 1 persistent block per CU

typedef __attribute__((ext_vector_type(8))) short short8;
typedef __attribute__((ext_vector_type(4))) float f32x4;

__device__ inline unsigned short f2bf(float f) {
    union { float f; unsigned u; } c; c.f = f;
    unsigned u = c.u;
    return (unsigned short)((u + 0x7fffu + ((u >> 16) & 1u)) >> 16);
}
__device__ inline float bf2f(unsigned short h) {
    union { unsigned u; float f; } c; c.u = ((unsigned)h) << 16;
    return c.f;
}

// Prep: wdg[b][d]=bf16(w_down*gamma), wub=bf16(w_up), c1/c2 reductions (R0 version).
__global__ void prep_kernel(const float* __restrict__ w_down, const float* __restrict__ w_up,
                            const float* __restrict__ gamma, const float* __restrict__ beta,
                            unsigned short* __restrict__ wdg, unsigned short* __restrict__ wub,
                            float* __restrict__ c1, float* __restrict__ c2) {
    int blk = blockIdx.x;
    if (blk < 384) {
        int i = blk * 256 + threadIdx.x;          // < 64*1536
        int d = i % EMBED;
        wdg[i] = f2bf(w_down[i] * gamma[d]);      // fold LN gamma into down-weights
        wub[i] = f2bf(w_up[i]);
        return;
    }
    int b = blk - 384;                            // 0..63
    int t = threadIdx.x;
    float s1 = 0.f, s2 = 0.f;
    for (int d = t; d < EMBED; d += 256) {
        float w = w_down[b * EMBED + d];
        s1 += gamma[d] * w;
        s2 += beta[d] * w;
    }
    #pragma unroll
    for (int m = 1; m < 64; m <<= 1) { s1 += __shfl_xor(s1, m); s2 += __shfl_xor(s2, m); }
    __shared__ float r1[4], r2[4];
    int wave = t >> 6, lane = t & 63;
    if (lane == 0) { r1[wave] = s1; r2[wave] = s2; }
    __syncthreads();
    if (t == 0) {
        c1[b] = r1[0] + r1[1] + r1[2] + r1[3];
        c2[b] = r2[0] + r2[1] + r2[2] + r2[3];
    }
}

// Producer/consumer persistent kernel. 512 threads = 8 waves, 1 block/CU.
// Waves 0-3 (producers): load x f32 (tile it), LN stats, cvt->bf16, write xs[pb].
// Waves 4-7 (consumers): GEMM1 + GELU + GEMM2 + L2-norm + store from xs[cb] (tile it-1).
// xs double-buffered: producer load-service overlaps consumer GEMM1; producer cvt
// overlaps consumer GEMM2. HBM reads are issued every iteration -> sustained in-flight
// bytes (the latency fix rounds 1-4 failed to get from same-stream prefetch).
// 2 barriers per tile. Per-path register peaks don't coincide (v dead at barrier B,
// cc dead at barrier A) -> no spill at (512,1).
__global__ __launch_bounds__(512, 1) void fused_kernel(
    const float* __restrict__ x, const float* __restrict__ b_down,
    const float* __restrict__ b_up,
    const unsigned short* __restrict__ wdg, const unsigned short* __restrict__ wub,
    const float* __restrict__ c1, const float* __restrict__ c2,
    float* __restrict__ out, int ntiles, int nblk)
{
    __shared__ unsigned short xs[2][16 * XS_STRIDE];  // bf16(x) double buffer
    __shared__ unsigned short gs[16 * GS_STRIDE];     // bf16 gelu output [token][b]
    __shared__ float mean_s[2][16], rstd_s[2][16], sumsq_s[2][16];

    const int tid  = threadIdx.x;
    const int wave = tid >> 6, lane = tid & 63;
    const int l16  = lane & 15, quad = lane >> 4;
    const int cw   = wave - 4;                        // consumer wave id 0..3
    const int bid  = blockIdx.x;

    float4 v[4][6];                                   // producer: 24 float4 in flight
    f32x4 cc[24];                                     // consumer: GEMM2 accumulators

    for (int it = 0; it <= nblk; ++it) {
        const int pb = it & 1;                        // produce buffer
        const int cb = pb ^ 1;                        // consume buffer
        const int q  = it & 1;                        // sumsq parity
        const long tprod = (long)bid * nblk + it;     // tile being produced
        const long tcons = tprod - 1;                 // tile being consumed
        const bool pact = (wave < 4)  && (it < nblk) && (tprod < ntiles);
        const bool cact = (wave >= 4) && (it > 0)    && (tcons < ntiles);

        // ---- region 1: producers issue loads (tile it) | consumers GEMM1+GELU (tile it-1)
        if (pact) {
            const long row0 = tprod * 16;
            #pragma unroll
            for (int j = 0; j < 4; ++j) {
                const float4* xp = (const float4*)(x + (row0 + wave * 4 + j) * EMBED);
                #pragma unroll
                for (int k = 0; k < 6; ++k) v[j][k] = xp[lane + 64 * k];
            }
        } else if (cact) {
            // GEMM1: t[token 16][b 16/wave] = x . (gamma*w_down)^T, K=1536
            f32x4 acc = {0.f, 0.f, 0.f, 0.f};
            {
                const unsigned short* arow = &xs[cb][l16 * XS_STRIDE];              // A[m=l16][k]
                const unsigned short* brow = wdg + (size_t)(cw * 16 + l16) * EMBED; // W[b=l16][k]
                #pragma unroll 4
                for (int kk = 0; kk < 48; ++kk) {
                    int ko = kk * 32 + quad * 8;
                    short8 a = *(const short8*)(arow + ko);
                    short8 b = *(const short8*)(brow + ko);
                    acc = __builtin_amdgcn_mfma_f32_16x16x32_bf16(a, b, acc, 0, 0, 0);
                }
            }
            // epilogue: LN scalar corrections + bias + exact GELU -> gs[token][b]
            int bg = cw * 16 + l16;
            float c1v = c1[bg], c2v = c2[bg], bdv = b_down[bg];
            #pragma unroll
            for (int reg = 0; reg < 4; ++reg) {
                int r = quad * 4 + reg;               // token = (lane>>4)*4 + reg
                float rs = rstd_s[cb][r];
                float vv = rs * acc[reg] - rs * mean_s[cb][r] * c1v + c2v + bdv;
                float g = 0.5f * vv * (1.f + erff(vv * 0.70710678118654752f));
                gs[r * GS_STRIDE + bg] = f2bf(g);
            }
        }
        __syncthreads();  // A: gs ready (consumers); producer loads drained into v

        // ---- region 2: producers stats+cvt+stage xs[pb] | consumers GEMM2+sumsq ----
        if (pact) {
            #pragma unroll
            for (int j = 0; j < 4; ++j) {
                int lr = wave * 4 + j;
                float s = 0.f, ss = 0.f;
                #pragma unroll
                for (int k = 0; k < 6; ++k) {
                    s  += v[j][k].x + v[j][k].y + v[j][k].z + v[j][k].w;
                    ss += v[j][k].x * v[j][k].x + v[j][k].y * v[j][k].y
                        + v[j][k].z * v[j][k].z + v[j][k].w * v[j][k].w;
                }
                #pragma unroll
                for (int m = 1; m < 64; m <<= 1) { s += __shfl_xor(s, m); ss += __shfl_xor(ss, m); }
                float mean = s * (1.f / EMBED);
                float var  = ss * (1.f / EMBED) - mean * mean;
                if (lane == 0) {
                    mean_s[pb][lr] = mean;
                    rstd_s[pb][lr] = rsqrtf(var + 1e-5f);
                }
                #pragma unroll
                for (int k = 0; k < 6; ++k) {
                    ushort4 p;
                    p.x = f2bf(v[j][k].x); p.y = f2bf(v[j][k].y);
                    p.z = f2bf(v[j][k].z); p.w = f2bf(v[j][k].w);
                    *(ushort4*)(&xs[pb][lr * XS_STRIDE + 4 * (lane + 64 * k)]) = p;
                }
            }
        } else if (wave >= 4) {
            if (cw == 0 && lane < 16) sumsq_s[q ^ 1][lane] = 0.f;  // prep next tile's acc
            if (cact) {
                // GEMM2 (transposed): D[m=d 16][n=token 16] = w_up_tile . g^T + (x + b_up)
                short8 gb0 = *(const short8*)(&gs[l16 * GS_STRIDE + quad * 8]);
                short8 gb1 = *(const short8*)(&gs[l16 * GS_STRIDE + 32 + quad * 8]);
                const int dbase = cw * 384;
                float sqs = 0.f;
                #pragma unroll
                for (int t = 0; t < 24; ++t) {
                    int d0 = dbase + t * 16;
                    int dm = d0 + quad * 4;                                  // 4 consecutive d
                    float4 bu = *(const float4*)(b_up + dm);
                    ushort4 rx = *(const ushort4*)(&xs[cb][l16 * XS_STRIDE + dm]);
                    f32x4 c;
                    c[0] = bf2f(rx.x) + bu.x;
                    c[1] = bf2f(rx.y) + bu.y;
                    c[2] = bf2f(rx.z) + bu.z;
                    c[3] = bf2f(rx.w) + bu.w;
                    const unsigned short* wrow = wub + (size_t)(d0 + l16) * 64;
                    short8 a0 = *(const short8*)(wrow + quad * 8);
                    short8 a1 = *(const short8*)(wrow + 32 + quad * 8);
                    c = __builtin_amdgcn_mfma_f32_16x16x32_bf16(a0, gb0, c, 0, 0, 0);
                    c = __builtin_amdgcn_mfma_f32_16x16x32_bf16(a1, gb1, c, 0, 0, 0);
                    cc[t] = c;
                    sqs += c[0] * c[0] + c[1] * c[1] + c[2] * c[2] + c[3] * c[3];
                }
                sqs += __shfl_xor(sqs, 16);
                sqs += __shfl_xor(sqs, 32);
                if (lane < 16) atomicAdd(&sumsq_s[q][l16], sqs);
            }
        }
        __syncthreads();  // B: sumsq ready; xs[pb] fully staged

        // ---- region 3: consumers normalize + store (registers only) ----
        if (cact) {
            const float inv = 1.f / fmaxf(sqrtf(sumsq_s[q][l16]), 1e-12f);
            float* orow = out + (tcons * 16 + l16) * EMBED;
            const int dbase = cw * 384;
            #pragma unroll
            for (int t = 0; t < 24; ++t) {
                int dm = dbase + t * 16 + quad * 4;
                f32x4 c = cc[t];
                float4 o;
                o.x = c[0] * inv; o.y = c[1] * inv; o.z = c[2] * inv; o.w = c[3] * inv;
                *(float4*)(orow + dm) = o;   // 16 B/lane store
            }
        }
    }
}

extern "C" void kernel_launch(void* const* d_in, const int* in_sizes, int n_in,
                              void* d_out, int out_size, void* d_ws, size_t ws_size,
                              hipStream_t stream)
{
    const float* x      = (const float*)d_in[0];
    const float* w_down = (const float*)d_in[1];
    const float* b_down = (const float*)d_in[2];
    const float* w_up   = (const float*)d_in[3];
    const float* b_up   = (const float*)d_in[4];
    const float* gamma  = (const float*)d_in[5];
    const float* beta   = (const float*)d_in[6];
    float* out = (float*)d_out;

    const int N = in_sizes[0] / EMBED;  // 32768, multiple of 16
    const int ntiles = N / 16;
    const int nblk = (ntiles + NBLOCKS - 1) / NBLOCKS;  // tiles per block (8)

    unsigned short* wdg = (unsigned short*)d_ws;
    unsigned short* wub = wdg + BN * EMBED;
    float* c1 = (float*)(wub + BN * EMBED);
    float* c2 = c1 + BN;

    prep_kernel<<<384 + BN, 256, 0, stream>>>(w_down, w_up, gamma, beta, wdg, wub, c1, c2);
    fused_kernel<<<NBLOCKS, 512, 0, stream>>>(x, b_down, b_up, wdg, wub, c1, c2, out,
                                              ntiles, nblk);
}

// Round 6
// 524.188 us; speedup vs baseline: 1.0795x; 1.0795x over previous
//
#include <hip/hip_runtime.h>
#include <math.h>

#define EMBED 1536
#define BN 64
#define GS_STRIDE 80     // shorts; row stride 160 B -> 16B aligned

typedef __attribute__((ext_vector_type(8))) short short8;
typedef __attribute__((ext_vector_type(4))) float f32x4;

__device__ inline unsigned short f2bf(float f) {
    union { float f; unsigned u; } c; c.f = f;
    unsigned u = c.u;
    return (unsigned short)((u + 0x7fffu + ((u >> 16) & 1u)) >> 16);
}

// Prep: wdg[b][d]=bf16(w_down*gamma), wub=bf16(w_up), c1/c2 reductions.
__global__ void prep_kernel(const float* __restrict__ w_down, const float* __restrict__ w_up,
                            const float* __restrict__ gamma, const float* __restrict__ beta,
                            unsigned short* __restrict__ wdg, unsigned short* __restrict__ wub,
                            float* __restrict__ c1, float* __restrict__ c2) {
    int blk = blockIdx.x;
    if (blk < 384) {
        int i = blk * 256 + threadIdx.x;          // < 64*1536
        int d = i % EMBED;
        wdg[i] = f2bf(w_down[i] * gamma[d]);      // fold LN gamma into down-weights
        wub[i] = f2bf(w_up[i]);
        return;
    }
    int b = blk - 384;                            // 0..63
    int t = threadIdx.x;
    float s1 = 0.f, s2 = 0.f;
    for (int d = t; d < EMBED; d += 256) {
        float w = w_down[b * EMBED + d];
        s1 += gamma[d] * w;
        s2 += beta[d] * w;
    }
    #pragma unroll
    for (int m = 1; m < 64; m <<= 1) { s1 += __shfl_xor(s1, m); s2 += __shfl_xor(s2, m); }
    __shared__ float r1[4], r2[4];
    int wave = t >> 6, lane = t & 63;
    if (lane == 0) { r1[wave] = s1; r2[wave] = s2; }
    __syncthreads();
    if (t == 0) {
        c1[b] = r1[0] + r1[1] + r1[2] + r1[3];
        c2[b] = r2[0] + r2[1] + r2[2] + r2[3];
    }
}

// Fused kernel, NO staging phase: GEMM1 streams x f32 directly from global in the MFMA
// A-fragment pattern (lane l16 = row, 32B at kk*32+quad*8; 16 rows x 128B segments per
// fragment -> coalesced), converts to bf16 in flight, and fuses the LN stats into the same
// pass (each wave redundantly computes all 16 rows' stats from its own stream -> identical
// results, no stats barrier). GEMM2 reads the residual x f32 straight from L2 (tile hot).
// HBM loads are therefore issued continuously through ~70% of the block lifetime instead
// of a front burst behind a barrier (the R0-R5 duty-cycle cap). LDS = gs + sumsq only
// (~3 KB); 2 barriers per block. cc[24] fits at (256,1) - no spill (R5 lesson).
__global__ __launch_bounds__(256, 1) void fused_kernel(
    const float* __restrict__ x, const float* __restrict__ b_down,
    const float* __restrict__ b_up,
    const unsigned short* __restrict__ wdg, const unsigned short* __restrict__ wub,
    const float* __restrict__ c1, const float* __restrict__ c2,
    float* __restrict__ out)
{
    __shared__ unsigned short gs[16 * GS_STRIDE];  // bf16 gelu output [token][b]
    __shared__ float sumsq_s[16];

    const int tid  = threadIdx.x;
    const int wave = tid >> 6, lane = tid & 63;
    const int l16  = lane & 15, quad = lane >> 4;
    const long row0 = (long)blockIdx.x * 16;
    const float* xrow = x + (row0 + l16) * EMBED;  // lane's row for GEMM1-A and GEMM2 residual

    if (tid < 16) sumsq_s[tid] = 0.f;

    // ---- GEMM1 + fused LN stats: acc[token][b] = x . (gamma*w_down)^T, K=1536 ----
    f32x4 acc = {0.f, 0.f, 0.f, 0.f};
    float s = 0.f, ss = 0.f;                       // partials for row l16 (this lane's k-slice)
    {
        const unsigned short* brow = wdg + (size_t)(wave * 16 + l16) * EMBED; // W[b=l16][k]
        #pragma unroll 4
        for (int kk = 0; kk < 48; ++kk) {
            int ko = kk * 32 + quad * 8;
            float4 a0 = *(const float4*)(xrow + ko);
            float4 a1 = *(const float4*)(xrow + ko + 4);
            short8 b = *(const short8*)(brow + ko);
            s  += (a0.x + a0.y) + (a0.z + a0.w) + (a1.x + a1.y) + (a1.z + a1.w);
            ss += a0.x * a0.x + a0.y * a0.y + a0.z * a0.z + a0.w * a0.w
                + a1.x * a1.x + a1.y * a1.y + a1.z * a1.z + a1.w * a1.w;
            short8 af;
            af[0] = (short)f2bf(a0.x); af[1] = (short)f2bf(a0.y);
            af[2] = (short)f2bf(a0.z); af[3] = (short)f2bf(a0.w);
            af[4] = (short)f2bf(a1.x); af[5] = (short)f2bf(a1.y);
            af[6] = (short)f2bf(a1.z); af[7] = (short)f2bf(a1.w);
            acc = __builtin_amdgcn_mfma_f32_16x16x32_bf16(af, b, acc, 0, 0, 0);
        }
    }
    // finish stats: sum the 4 quads of each row -> every lane holds row-l16 totals
    s  += __shfl_xor(s, 16);  s  += __shfl_xor(s, 32);
    ss += __shfl_xor(ss, 16); ss += __shfl_xor(ss, 32);
    float mean = s * (1.f / EMBED);
    float rstd = rsqrtf(ss * (1.f / EMBED) - mean * mean + 1e-5f);
    float rsm  = rstd * mean;
    // epilogue: LN scalar corrections + bias + exact GELU -> gs[token][b]
    {
        int bg = wave * 16 + l16;  // D col = lane&15
        float c1v = c1[bg], c2v = c2[bg], bdv = b_down[bg];
        #pragma unroll
        for (int reg = 0; reg < 4; ++reg) {
            int r = quad * 4 + reg;            // D row (token); stats live in lane r
            float rs = __shfl(rstd, r);
            float rm = __shfl(rsm, r);
            float vv = rs * acc[reg] - rm * c1v + c2v + bdv;
            float g = 0.5f * vv * (1.f + erff(vv * 0.70710678118654752f));
            gs[r * GS_STRIDE + bg] = f2bf(g);
        }
    }
    __syncthreads();  // B1: gs ready (sumsq_s init also covered)

    // ---- GEMM2 (transposed tile): D[m=d 16][n=token 16] = w_up_tile . g^T + (x + b_up) ----
    short8 gb0 = *(const short8*)(&gs[l16 * GS_STRIDE + quad * 8]);
    short8 gb1 = *(const short8*)(&gs[l16 * GS_STRIDE + 32 + quad * 8]);
    const int dbase = wave * 384;
    f32x4 cc[24];
    float sqs = 0.f;
    #pragma unroll
    for (int t = 0; t < 24; ++t) {
        int d0 = dbase + t * 16;
        int dm = d0 + quad * 4;                                  // C rows: 4 consecutive d
        float4 bu = *(const float4*)(b_up + dm);
        float4 rx = *(const float4*)(xrow + dm);                 // residual f32, L2-hot
        f32x4 c;
        c[0] = rx.x + bu.x;
        c[1] = rx.y + bu.y;
        c[2] = rx.z + bu.z;
        c[3] = rx.w + bu.w;
        const unsigned short* wrow = wub + (size_t)(d0 + l16) * 64;  // A[m=l16][k]
        short8 a0 = *(const short8*)(wrow + quad * 8);
        short8 a1 = *(const short8*)(wrow + 32 + quad * 8);
        c = __builtin_amdgcn_mfma_f32_16x16x32_bf16(a0, gb0, c, 0, 0, 0);
        c = __builtin_amdgcn_mfma_f32_16x16x32_bf16(a1, gb1, c, 0, 0, 0);
        cc[t] = c;
        sqs += c[0] * c[0] + c[1] * c[1] + c[2] * c[2] + c[3] * c[3];
    }
    // per-token sumsq: lane's partial is for token l16 over this wave's 384 d
    sqs += __shfl_xor(sqs, 16);
    sqs += __shfl_xor(sqs, 32);
    if (lane < 16) atomicAdd(&sumsq_s[l16], sqs);
    __syncthreads();  // B2: sumsq complete

    const float inv = 1.f / fmaxf(sqrtf(sumsq_s[l16]), 1e-12f);
    float* orow = out + (row0 + l16) * EMBED;
    #pragma unroll
    for (int t = 0; t < 24; ++t) {
        int dm = dbase + t * 16 + quad * 4;
        f32x4 c = cc[t];
        float4 o;
        o.x = c[0] * inv; o.y = c[1] * inv; o.z = c[2] * inv; o.w = c[3] * inv;
        *(float4*)(orow + dm) = o;   // 16 B/lane store
    }
}

extern "C" void kernel_launch(void* const* d_in, const int* in_sizes, int n_in,
                              void* d_out, int out_size, void* d_ws, size_t ws_size,
                              hipStream_t stream)
{
    const float* x      = (const float*)d_in[0];
    const float* w_down = (const float*)d_in[1];
    const float* b_down = (const float*)d_in[2];
    const float* w_up   = (const float*)d_in[3];
    const float* b_up   = (const float*)d_in[4];
    const float* gamma  = (const float*)d_in[5];
    const float* beta   = (const float*)d_in[6];
    float* out = (float*)d_out;

    const int N = in_sizes[0] / EMBED;  // 32768, multiple of 16

    unsigned short* wdg = (unsigned short*)d_ws;
    unsigned short* wub = wdg + BN * EMBED;
    float* c1 = (float*)(wub + BN * EMBED);
    float* c2 = c1 + BN;

    prep_kernel<<<384 + BN, 256, 0, stream>>>(w_down, w_up, gamma, beta, wdg, wub, c1, c2);
    fused_kernel<<<N / 16, 256, 0, stream>>>(x, b_down, b_up, wdg, wub, c1, c2, out);
}